// Round 1
// baseline (2336.512 us; speedup 1.0000x reference)
//
#include <hip/hip_runtime.h>

#define IN_C   512
#define HID_C  256
#define OUT_C  64
#define KSTEPS 10

// ---------------------------------------------------------------------------
// CSR build: histogram by dst, exclusive scan, scatter (src, norm) pairs.
// ---------------------------------------------------------------------------
__global__ void k_init(int* __restrict__ cnt, int* __restrict__ fill, int n) {
    int i = blockIdx.x * blockDim.x + threadIdx.x;
    if (i < n) { cnt[i] = 0; fill[i] = 0; }
}

__global__ void k_hist(const int* __restrict__ ei, int* __restrict__ cnt, int E) {
    int e = blockIdx.x * blockDim.x + threadIdx.x;
    if (e < E) atomicAdd(&cnt[ei[E + e]], 1);
}

__global__ void k_dinv(const int* __restrict__ cnt, float* __restrict__ dinv, int n) {
    int i = blockIdx.x * blockDim.x + threadIdx.x;
    // deg includes the self loop -> always >= 1
    if (i < n) dinv[i] = rsqrtf((float)cnt[i] + 1.0f);
}

// inclusive scan within 256-block, write to rowptr[i+1], block sums to bsum
__global__ void k_scan1(const int* __restrict__ cnt, int* __restrict__ rowptr,
                        int* __restrict__ bsum, int n) {
    __shared__ int sh[256];
    int i = blockIdx.x * 256 + threadIdx.x;
    int v = (i < n) ? cnt[i] : 0;
    sh[threadIdx.x] = v;
    __syncthreads();
    for (int off = 1; off < 256; off <<= 1) {
        int t = (threadIdx.x >= off) ? sh[threadIdx.x - off] : 0;
        __syncthreads();
        sh[threadIdx.x] += t;
        __syncthreads();
    }
    if (i < n) rowptr[i + 1] = sh[threadIdx.x];
    if (threadIdx.x == 255) bsum[blockIdx.x] = sh[255];
}

// single-block exclusive scan of block sums (nb <= 512)
__global__ void k_scan2(int* __restrict__ bsum, int nb) {
    __shared__ int sh[512];
    int t = threadIdx.x;
    int v = (t < nb) ? bsum[t] : 0;
    sh[t] = v;
    __syncthreads();
    for (int off = 1; off < 512; off <<= 1) {
        int u = (t >= off) ? sh[t - off] : 0;
        __syncthreads();
        sh[t] += u;
        __syncthreads();
    }
    int ex = (t == 0) ? 0 : sh[t - 1];
    if (t < nb) bsum[t] = ex;
}

__global__ void k_scan3(int* __restrict__ rowptr, const int* __restrict__ bsum, int n) {
    int i = blockIdx.x * blockDim.x + threadIdx.x;
    if (i < n) rowptr[i + 1] += bsum[i >> 8];
    if (i == 0) rowptr[0] = 0;
}

__global__ void k_scatter(const int* __restrict__ ei, const float* __restrict__ dinv,
                          const int* __restrict__ rowptr, int* __restrict__ fill,
                          int2* __restrict__ edges, int E) {
    int e = blockIdx.x * blockDim.x + threadIdx.x;
    if (e < E) {
        int s = ei[e], d = ei[E + e];
        float nv = dinv[s] * dinv[d];
        int pos = rowptr[d] + atomicAdd(&fill[d], 1);
        edges[pos] = make_int2(s, __float_as_int(nv));
    }
}

__global__ void k_tw2(const float* __restrict__ W2, float* __restrict__ w2t) {
    int i = blockIdx.x * blockDim.x + threadIdx.x;
    if (i < OUT_C * HID_C) {
        int o = i >> 8;      // W2 row (output channel)
        int c = i & 255;     // W2 col (hidden channel)
        w2t[c * OUT_C + o] = W2[i];
    }
}

// ---------------------------------------------------------------------------
// Fused MLP: h2 = relu(x@W1^T + b1) @ W2^T + b2
// Writes h2 -> bufA (x_0 for propagation) and temp[0]*h2 -> out.
// Block: 256 threads, 64 rows. LDS 64KB: stage1 tiles alias h1T buffer.
// ---------------------------------------------------------------------------
__global__ __launch_bounds__(256, 2) void k_mlp(
    const float* __restrict__ x, const float* __restrict__ W1,
    const float* __restrict__ b1, const float* __restrict__ w2t,
    const float* __restrict__ b2, const float* __restrict__ temp,
    float* __restrict__ h, float* __restrict__ out, int n)
{
    __shared__ float smem[16384];            // 64 KB
    float* xs  = smem;                       // [32][68]  x tile, transposed, padded
    float* ws1 = smem + 32 * 68;             // [32][260] W1 tile, transposed, padded
    float* h1T = smem;                       // [256][64] h1 tile (aliases stage1)

    const int tid  = threadIdx.x;
    const int tx   = tid & 15, ty = tid >> 4;
    const int row0 = blockIdx.x << 6;

    float acc[4][16];
#pragma unroll
    for (int i = 0; i < 4; ++i)
#pragma unroll
        for (int j = 0; j < 16; ++j) acc[i][j] = 0.f;

    for (int k0 = 0; k0 < IN_C; k0 += 32) {
        // x tile: 64 rows x 32 k -> xs[kk][r]
#pragma unroll
        for (int it = 0; it < 2; ++it) {
            int f = tid + it * 256;          // 0..511 float4 slots
            int r = f >> 3, kq = f & 7;
            float4 v = make_float4(0.f, 0.f, 0.f, 0.f);
            int gr = row0 + r;
            if (gr < n) v = *(const float4*)(x + (size_t)gr * IN_C + k0 + kq * 4);
            xs[(kq * 4 + 0) * 68 + r] = v.x;
            xs[(kq * 4 + 1) * 68 + r] = v.y;
            xs[(kq * 4 + 2) * 68 + r] = v.z;
            xs[(kq * 4 + 3) * 68 + r] = v.w;
        }
        // W1 tile: 256 hid x 32 k -> ws1[kk][c]
#pragma unroll
        for (int it = 0; it < 8; ++it) {
            int f = tid + it * 256;          // 0..2047 float4 slots
            int c = f >> 3, kq = f & 7;
            float4 v = *(const float4*)(W1 + (size_t)c * IN_C + k0 + kq * 4);
            ws1[(kq * 4 + 0) * 260 + c] = v.x;
            ws1[(kq * 4 + 1) * 260 + c] = v.y;
            ws1[(kq * 4 + 2) * 260 + c] = v.z;
            ws1[(kq * 4 + 3) * 260 + c] = v.w;
        }
        __syncthreads();
#pragma unroll
        for (int kk = 0; kk < 32; ++kk) {
            float4 xv = *(const float4*)(xs  + kk * 68  + ty * 4);
            float4 wa = *(const float4*)(ws1 + kk * 260 + tx * 16);
            float4 wb = *(const float4*)(ws1 + kk * 260 + tx * 16 + 4);
            float4 wc = *(const float4*)(ws1 + kk * 260 + tx * 16 + 8);
            float4 wd = *(const float4*)(ws1 + kk * 260 + tx * 16 + 12);
            float xr[4]  = {xv.x, xv.y, xv.z, xv.w};
            float wr[16] = {wa.x, wa.y, wa.z, wa.w, wb.x, wb.y, wb.z, wb.w,
                            wc.x, wc.y, wc.z, wc.w, wd.x, wd.y, wd.z, wd.w};
#pragma unroll
            for (int i = 0; i < 4; ++i)
#pragma unroll
                for (int j = 0; j < 16; ++j)
                    acc[i][j] = fmaf(xr[i], wr[j], acc[i][j]);
        }
        __syncthreads();
    }

    // bias + relu -> h1T[c][r]
#pragma unroll
    for (int j = 0; j < 16; ++j) {
        float bb = b1[tx * 16 + j];
#pragma unroll
        for (int i = 0; i < 4; ++i) {
            float v = fmaxf(acc[i][j] + bb, 0.f);
            h1T[(tx * 16 + j) * 64 + ty * 4 + i] = v;
        }
    }
    __syncthreads();

    // stage 2: h2[r][o] = sum_c h1[r][c] * W2[o][c]; rows ty*4+i, cols tx*4+j
    float a2[4][4];
#pragma unroll
    for (int i = 0; i < 4; ++i)
#pragma unroll
        for (int j = 0; j < 4; ++j) a2[i][j] = 0.f;

    for (int c = 0; c < HID_C; ++c) {
        float4 hv = *(const float4*)(h1T + c * 64 + ty * 4);
        float4 wv = *(const float4*)(w2t + c * OUT_C + tx * 4);
        float hr[4] = {hv.x, hv.y, hv.z, hv.w};
        float wr[4] = {wv.x, wv.y, wv.z, wv.w};
#pragma unroll
        for (int i = 0; i < 4; ++i)
#pragma unroll
            for (int j = 0; j < 4; ++j)
                a2[i][j] = fmaf(hr[i], wr[j], a2[i][j]);
    }

    float4 bbv = *(const float4*)(b2 + tx * 4);
    float t0 = temp[0];
#pragma unroll
    for (int i = 0; i < 4; ++i) {
        int gr = row0 + ty * 4 + i;
        if (gr < n) {
            float4 v;
            v.x = a2[i][0] + bbv.x;
            v.y = a2[i][1] + bbv.y;
            v.z = a2[i][2] + bbv.z;
            v.w = a2[i][3] + bbv.w;
            *(float4*)(h + (size_t)gr * OUT_C + tx * 4) = v;
            float4 ov = make_float4(t0 * v.x, t0 * v.y, t0 * v.z, t0 * v.w);
            *(float4*)(out + (size_t)gr * OUT_C + tx * 4) = ov;
        }
    }
}

// ---------------------------------------------------------------------------
// One propagation step, gather-form (no fp atomics). One wave per dst node,
// lane = channel. Fuses: self-loop term, hidden += gamma*xk, write next buf.
// ---------------------------------------------------------------------------
__global__ void k_prop(const int* __restrict__ rowptr, const int2* __restrict__ edges,
                       const float* __restrict__ cur, float* __restrict__ nxt,
                       float* __restrict__ out, const float* __restrict__ dinv,
                       const float* __restrict__ temp, int k, int n)
{
    const int lane = threadIdx.x & 63;
    const int wid  = (blockIdx.x * blockDim.x + threadIdx.x) >> 6;
    const int nw   = (gridDim.x * blockDim.x) >> 6;
    const float gamma = temp[k];
    for (int d = wid; d < n; d += nw) {
        float di  = dinv[d];
        float acc = di * di * cur[(size_t)d * OUT_C + lane];   // self loop
        int b = rowptr[d], en = rowptr[d + 1];
        for (int i = b; i < en; ++i) {
            int2 ed = edges[i];                                 // wave-uniform 8B
            acc = fmaf(__int_as_float(ed.y), cur[(size_t)ed.x * OUT_C + lane], acc);
        }
        size_t o = (size_t)d * OUT_C + lane;
        nxt[o] = acc;
        out[o] += gamma * acc;
    }
}

// ---------------------------------------------------------------------------
extern "C" void kernel_launch(void* const* d_in, const int* in_sizes, int n_in,
                              void* d_out, int out_size, void* d_ws, size_t ws_size,
                              hipStream_t stream)
{
    const float* x    = (const float*)d_in[0];
    const int*   ei   = (const int*)d_in[1];
    const float* W1   = (const float*)d_in[2];
    const float* b1   = (const float*)d_in[3];
    const float* W2   = (const float*)d_in[4];
    const float* b2   = (const float*)d_in[5];
    const float* temp = (const float*)d_in[6];
    float* out = (float*)d_out;

    const int N = in_sizes[0] / IN_C;
    const int E = in_sizes[1] / 2;

    // workspace layout (bytes)
    char* ws = (char*)d_ws;
    float* bufA  = (float*)ws;                                   // N*64 f32
    float* bufB  = (float*)(ws + (size_t)N * OUT_C * 4);         // N*64 f32
    int2*  edges = (int2*)(ws + (size_t)N * OUT_C * 8);          // E int2
    float* dinv  = (float*)(ws + (size_t)N * OUT_C * 8 + (size_t)E * 8);
    int*   cnt    = (int*)((char*)dinv + (size_t)N * 4);
    int*   fill   = cnt + N;
    int*   rowptr = fill + N;
    int*   bsum   = rowptr + (N + 1);
    float* w2t    = (float*)(bsum + 512);

    const int nbN = (N + 255) / 256;
    const int nbE = (E + 255) / 256;

    k_init   <<<nbN, 256, 0, stream>>>(cnt, fill, N);
    k_hist   <<<nbE, 256, 0, stream>>>(ei, cnt, E);
    k_dinv   <<<nbN, 256, 0, stream>>>(cnt, dinv, N);
    k_scan1  <<<nbN, 256, 0, stream>>>(cnt, rowptr, bsum, N);
    k_scan2  <<<1,   512, 0, stream>>>(bsum, nbN);
    k_scan3  <<<nbN, 256, 0, stream>>>(rowptr, bsum, N);
    k_scatter<<<nbE, 256, 0, stream>>>(ei, dinv, rowptr, fill, edges, E);
    k_tw2    <<<(OUT_C * HID_C + 255) / 256, 256, 0, stream>>>(W2, w2t);

    k_mlp<<<(N + 63) / 64, 256, 0, stream>>>(x, W1, b1, w2t, b2, temp, bufA, out, N);

    float* cur = bufA;
    float* nxt = bufB;
    for (int k = 1; k <= KSTEPS; ++k) {
        k_prop<<<2048, 256, 0, stream>>>(rowptr, edges, cur, nxt, out, dinv, temp, k, N);
        float* t = cur; cur = nxt; nxt = t;
    }
}

// Round 2
// 1012.904 us; speedup vs baseline: 2.3067x; 2.3067x over previous
//
#include <hip/hip_runtime.h>

#define IN_C   512
#define HID_C  256
#define OUT_C  64
#define KSTEPS 10

typedef __attribute__((ext_vector_type(8))) short bf16x8;
typedef __attribute__((ext_vector_type(4))) float f32x4;

__device__ __forceinline__ uint f2bf(float f) {
    uint u = __float_as_uint(f);
    return (u + 0x7fffu + ((u >> 16) & 1u)) >> 16;   // RNE to bf16
}

// ---------------------------------------------------------------------------
// CSR build: histogram by dst, exclusive scan, scatter (src, norm) pairs.
// ---------------------------------------------------------------------------
__global__ void k_init(int* __restrict__ cnt, int* __restrict__ fill, int n) {
    int i = blockIdx.x * blockDim.x + threadIdx.x;
    if (i < n) { cnt[i] = 0; fill[i] = 0; }
}

__global__ void k_hist(const int* __restrict__ ei, int* __restrict__ cnt, int E) {
    int e = blockIdx.x * blockDim.x + threadIdx.x;
    if (e < E) atomicAdd(&cnt[ei[E + e]], 1);
}

__global__ void k_dinv(const int* __restrict__ cnt, float* __restrict__ dinv, int n) {
    int i = blockIdx.x * blockDim.x + threadIdx.x;
    if (i < n) dinv[i] = rsqrtf((float)cnt[i] + 1.0f);   // deg includes self loop
}

__global__ void k_scan1(const int* __restrict__ cnt, int* __restrict__ rowptr,
                        int* __restrict__ bsum, int n) {
    __shared__ int sh[256];
    int i = blockIdx.x * 256 + threadIdx.x;
    int v = (i < n) ? cnt[i] : 0;
    sh[threadIdx.x] = v;
    __syncthreads();
    for (int off = 1; off < 256; off <<= 1) {
        int t = (threadIdx.x >= off) ? sh[threadIdx.x - off] : 0;
        __syncthreads();
        sh[threadIdx.x] += t;
        __syncthreads();
    }
    if (i < n) rowptr[i + 1] = sh[threadIdx.x];
    if (threadIdx.x == 255) bsum[blockIdx.x] = sh[255];
}

__global__ void k_scan2(int* __restrict__ bsum, int nb) {
    __shared__ int sh[512];
    int t = threadIdx.x;
    int v = (t < nb) ? bsum[t] : 0;
    sh[t] = v;
    __syncthreads();
    for (int off = 1; off < 512; off <<= 1) {
        int u = (t >= off) ? sh[t - off] : 0;
        __syncthreads();
        sh[t] += u;
        __syncthreads();
    }
    int ex = (t == 0) ? 0 : sh[t - 1];
    if (t < nb) bsum[t] = ex;
}

__global__ void k_scan3(int* __restrict__ rowptr, const int* __restrict__ bsum, int n) {
    int i = blockIdx.x * blockDim.x + threadIdx.x;
    if (i < n) rowptr[i + 1] += bsum[i >> 8];
    if (i == 0) rowptr[0] = 0;
}

__global__ void k_scatter(const int* __restrict__ ei, const float* __restrict__ dinv,
                          const int* __restrict__ rowptr, int* __restrict__ fill,
                          int2* __restrict__ edges, int E) {
    int e = blockIdx.x * blockDim.x + threadIdx.x;
    if (e < E) {
        int s = ei[e], d = ei[E + e];
        float nv = dinv[s] * dinv[d];
        int pos = rowptr[d] + atomicAdd(&fill[d], 1);
        edges[pos] = make_int2(s, __float_as_int(nv));
    }
}

// f32 -> bf16 conversion for weights
__global__ void k_cvt(const float* __restrict__ src, ushort* __restrict__ dst, int n) {
    int i = blockIdx.x * blockDim.x + threadIdx.x;
    if (i < n) dst[i] = (ushort)f2bf(src[i]);
}

// ---------------------------------------------------------------------------
// Fused MFMA MLP: h2 = relu(x@W1^T + b1) @ W2^T + b2  (bf16 in, fp32 accum)
// Block: 256 thr (4 waves), BM=64 rows. Stage1: cols split across waves
// (wave w -> hidden cols [64w,64w+64)), K-loop BK=64. h1 -> LDS bf16.
// Stage2: wave w -> rows [16w,16w+16), full 64 out cols.
// All LDS tiles XOR-swizzled: 16B-block index ^= (row&7)  (T2).
// ---------------------------------------------------------------------------
__global__ __launch_bounds__(256, 2) void k_mlp(
    const float* __restrict__ x, const ushort* __restrict__ W1b,
    const float* __restrict__ b1, const ushort* __restrict__ W2b,
    const float* __restrict__ b2, const float* __restrict__ temp,
    float* __restrict__ h, float* __restrict__ out, int n)
{
    __shared__ uint4 smem4[4096];            // 64 KB, 16B aligned
    char* smem = (char*)smem4;
    // phase 1: xs  = smem[0 .. 8K)      [64 rows][128 B]  (64 bf16/row)
    //          w1s = smem[8K .. 40K)    [256 rows][128 B]
    // phase 2: h1s = smem[0 .. 32K)     [64 rows][512 B]  (256 bf16/row)
    //          w2s = smem[32K .. 64K)   [64 rows][512 B]

    const int tid = threadIdx.x;
    const int lane = tid & 63;
    const int w    = tid >> 6;        // wave 0..3
    const int l15  = lane & 15;
    const int l4   = lane >> 4;       // 0..3
    const int row0 = blockIdx.x * 64;

    f32x4 acc[4][4];                  // [rf][nf]
#pragma unroll
    for (int i = 0; i < 4; ++i)
#pragma unroll
        for (int j = 0; j < 4; ++j) acc[i][j] = (f32x4){0.f, 0.f, 0.f, 0.f};

    for (int k0 = 0; k0 < IN_C; k0 += 64) {
        // stage X tile: 64 rows x 64 k, f32 -> bf16, swizzled
#pragma unroll
        for (int it = 0; it < 4; ++it) {
            int f  = tid + it * 256;          // float4 slot 0..1023
            int r  = f >> 4;                  // row 0..63
            int c4 = f & 15;                  // float4 idx within row
            int gr = row0 + r; if (gr >= n) gr = n - 1;
            float4 v = *(const float4*)(x + (size_t)gr * IN_C + k0 + c4 * 4);
            uint p0 = f2bf(v.x) | (f2bf(v.y) << 16);
            uint p1 = f2bf(v.z) | (f2bf(v.w) << 16);
            int boff = (c4 * 8) ^ ((r & 7) << 4);
            *(uint2*)(smem + r * 128 + boff) = make_uint2(p0, p1);
        }
        // stage W1 tile: 256 rows(hid) x 64 k bf16, swizzled (src already bf16)
#pragma unroll
        for (int it = 0; it < 8; ++it) {
            int m  = tid + it * 256;          // 16B-block 0..2047
            int nn = m >> 3, b = m & 7;
            uint4 v = *(const uint4*)(W1b + (size_t)nn * IN_C + k0 + b * 8);
            int bd = b ^ (nn & 7);
            *(uint4*)(smem + 8192 + nn * 128 + (bd << 4)) = v;
        }
        __syncthreads();
#pragma unroll
        for (int kk = 0; kk < 2; ++kk) {
            bf16x8 af[4], bfr[4];
            int kb = kk * 4 + l4;             // 16B-block in k
#pragma unroll
            for (int rf = 0; rf < 4; ++rf) {
                int r = rf * 16 + l15;
                af[rf] = *(const bf16x8*)(smem + r * 128 + ((kb ^ (r & 7)) << 4));
            }
#pragma unroll
            for (int nf = 0; nf < 4; ++nf) {
                int nn = w * 64 + nf * 16 + l15;
                bfr[nf] = *(const bf16x8*)(smem + 8192 + nn * 128 + ((kb ^ (nn & 7)) << 4));
            }
#pragma unroll
            for (int rf = 0; rf < 4; ++rf)
#pragma unroll
                for (int nf = 0; nf < 4; ++nf)
                    acc[rf][nf] = __builtin_amdgcn_mfma_f32_16x16x32_bf16(
                        af[rf], bfr[nf], acc[rf][nf], 0, 0, 0);
        }
        __syncthreads();
    }

    // bias + relu -> h1s bf16 swizzled; stage W2 tile
    float bias1[4];
#pragma unroll
    for (int nf = 0; nf < 4; ++nf) bias1[nf] = b1[w * 64 + nf * 16 + l15];
#pragma unroll
    for (int rf = 0; rf < 4; ++rf)
#pragma unroll
        for (int nf = 0; nf < 4; ++nf)
#pragma unroll
            for (int j = 0; j < 4; ++j) {
                int r = rf * 16 + l4 * 4 + j;
                int c = w * 64 + nf * 16 + l15;
                float v = fmaxf(acc[rf][nf][j] + bias1[nf], 0.f);
                int byte = r * 512 + ((((c >> 3) ^ (r & 7))) << 4) + (c & 7) * 2;
                *(ushort*)(smem + byte) = (ushort)f2bf(v);
            }
#pragma unroll
    for (int it = 0; it < 8; ++it) {
        int m  = tid + it * 256;              // 16B-block 0..2047
        int nn = m >> 5, b = m & 31;          // row = 512B = 32 blocks
        uint4 v = *(const uint4*)(W2b + (size_t)nn * HID_C + b * 8);
        int bd = b ^ (nn & 7);
        *(uint4*)(smem + 32768 + nn * 512 + (bd << 4)) = v;
    }
    __syncthreads();

    // stage 2 GEMM: rows slab per wave, K=256
    f32x4 acc2[4];
#pragma unroll
    for (int nf = 0; nf < 4; ++nf) acc2[nf] = (f32x4){0.f, 0.f, 0.f, 0.f};
#pragma unroll
    for (int kk = 0; kk < 8; ++kk) {
        int r = w * 16 + l15;
        int kb = kk * 4 + l4;
        bf16x8 a = *(const bf16x8*)(smem + r * 512 + ((kb ^ (r & 7)) << 4));
#pragma unroll
        for (int nf = 0; nf < 4; ++nf) {
            int nn = nf * 16 + l15;
            bf16x8 bb = *(const bf16x8*)(smem + 32768 + nn * 512 + ((kb ^ (nn & 7)) << 4));
            acc2[nf] = __builtin_amdgcn_mfma_f32_16x16x32_bf16(a, bb, acc2[nf], 0, 0, 0);
        }
    }

    float t0 = temp[0];
#pragma unroll
    for (int nf = 0; nf < 4; ++nf) {
        int c = nf * 16 + l15;
        float bias = b2[c];
#pragma unroll
        for (int j = 0; j < 4; ++j) {
            int gr = row0 + w * 16 + l4 * 4 + j;
            if (gr < n) {
                float v = acc2[nf][j] + bias;
                h[(size_t)gr * OUT_C + c]   = v;
                out[(size_t)gr * OUT_C + c] = t0 * v;
            }
        }
    }
}

// ---------------------------------------------------------------------------
// One propagation step, gather-form. One wave per dst node, lane = channel.
// Unrolled x4 with independent accumulators for memory-level parallelism.
// ---------------------------------------------------------------------------
__global__ __launch_bounds__(256) void k_prop(
    const int* __restrict__ rowptr, const int2* __restrict__ edges,
    const float* __restrict__ cur, float* __restrict__ nxt,
    float* __restrict__ out, const float* __restrict__ dinv,
    const float* __restrict__ temp, int k, int n)
{
    const int lane = threadIdx.x & 63;
    const int wid  = (blockIdx.x * blockDim.x + threadIdx.x) >> 6;
    const int nw   = (gridDim.x * blockDim.x) >> 6;
    const float gamma = temp[k];
    for (int d = wid; d < n; d += nw) {
        float di = dinv[d];
        size_t o = (size_t)d * OUT_C + lane;
        float a0 = di * di * cur[o], a1 = 0.f, a2 = 0.f, a3 = 0.f;
        int b = rowptr[d], en = rowptr[d + 1];
        int i = b;
        for (; i + 4 <= en; i += 4) {
            int2 e0 = edges[i], e1 = edges[i + 1], e2 = edges[i + 2], e3 = edges[i + 3];
            float v0 = cur[(size_t)e0.x * OUT_C + lane];
            float v1 = cur[(size_t)e1.x * OUT_C + lane];
            float v2 = cur[(size_t)e2.x * OUT_C + lane];
            float v3 = cur[(size_t)e3.x * OUT_C + lane];
            a0 = fmaf(__int_as_float(e0.y), v0, a0);
            a1 = fmaf(__int_as_float(e1.y), v1, a1);
            a2 = fmaf(__int_as_float(e2.y), v2, a2);
            a3 = fmaf(__int_as_float(e3.y), v3, a3);
        }
        for (; i < en; ++i) {
            int2 e = edges[i];
            a0 = fmaf(__int_as_float(e.y), cur[(size_t)e.x * OUT_C + lane], a0);
        }
        float acc = (a0 + a1) + (a2 + a3);
        nxt[o] = acc;
        out[o] += gamma * acc;
    }
}

// ---------------------------------------------------------------------------
extern "C" void kernel_launch(void* const* d_in, const int* in_sizes, int n_in,
                              void* d_out, int out_size, void* d_ws, size_t ws_size,
                              hipStream_t stream)
{
    const float* x    = (const float*)d_in[0];
    const int*   ei   = (const int*)d_in[1];
    const float* W1   = (const float*)d_in[2];
    const float* b1   = (const float*)d_in[3];
    const float* W2   = (const float*)d_in[4];
    const float* b2   = (const float*)d_in[5];
    const float* temp = (const float*)d_in[6];
    float* out = (float*)d_out;

    const int N = in_sizes[0] / IN_C;
    const int E = in_sizes[1] / 2;

    // workspace layout (16B-aligned chunks first)
    char* ws = (char*)d_ws;
    float*  bufA  = (float*)ws;                                    // N*64 f32
    float*  bufB  = (float*)(ws + (size_t)N * OUT_C * 4);          // N*64 f32
    int2*   edges = (int2*)(ws + (size_t)N * OUT_C * 8);           // E int2
    ushort* W1b   = (ushort*)(ws + (size_t)N * OUT_C * 8 + (size_t)E * 8);
    ushort* W2b   = W1b + HID_C * IN_C;                            // 131072 + 16384 ushort
    float*  dinv  = (float*)(W2b + OUT_C * HID_C);
    int*    cnt    = (int*)(dinv + N);
    int*    fill   = cnt + N;
    int*    rowptr = fill + N;
    int*    bsum   = rowptr + (N + 16);

    const int nbN = (N + 255) / 256;
    const int nbE = (E + 255) / 256;

    k_init   <<<nbN, 256, 0, stream>>>(cnt, fill, N);
    k_hist   <<<nbE, 256, 0, stream>>>(ei, cnt, E);
    k_dinv   <<<nbN, 256, 0, stream>>>(cnt, dinv, N);
    k_scan1  <<<nbN, 256, 0, stream>>>(cnt, rowptr, bsum, N);
    k_scan2  <<<1,   512, 0, stream>>>(bsum, nbN);
    k_scan3  <<<nbN, 256, 0, stream>>>(rowptr, bsum, N);
    k_scatter<<<nbE, 256, 0, stream>>>(ei, dinv, rowptr, fill, edges, E);
    k_cvt    <<<(HID_C * IN_C + 255) / 256, 256, 0, stream>>>(W1, W1b, HID_C * IN_C);
    k_cvt    <<<(OUT_C * HID_C + 255) / 256, 256, 0, stream>>>(W2, W2b, OUT_C * HID_C);

    k_mlp<<<(N + 63) / 64, 256, 0, stream>>>(x, W1b, b1, W2b, b2, temp, bufA, out, N);

    float* cur = bufA;
    float* nxt = bufB;
    for (int k = 1; k <= KSTEPS; ++k) {
        k_prop<<<2048, 256, 0, stream>>>(rowptr, edges, cur, nxt, out, dinv, temp, k, N);
        float* t = cur; cur = nxt; nxt = t;
    }
}

// Round 3
// 730.854 us; speedup vs baseline: 3.1970x; 1.3859x over previous
//
#include <hip/hip_runtime.h>

#define IN_C   512
#define HID_C  256
#define OUT_C  64
#define KSTEPS 10

typedef __attribute__((ext_vector_type(8))) short bf16x8;
typedef __attribute__((ext_vector_type(4))) float f32x4;

__device__ __forceinline__ uint f2bf(float f) {
    uint u = __float_as_uint(f);
    return (u + 0x7fffu + ((u >> 16) & 1u)) >> 16;   // RNE to bf16
}
__device__ __forceinline__ float bfl(uint u) { return __uint_as_float(u << 16); }
__device__ __forceinline__ float bfh(uint u) { return __uint_as_float(u & 0xffff0000u); }

// ---------------------------------------------------------------------------
// CSR build: histogram by dst, exclusive scan, scatter (src, norm) pairs.
// ---------------------------------------------------------------------------
__global__ void k_init(int* __restrict__ cnt, int* __restrict__ fill, int n) {
    int i = blockIdx.x * blockDim.x + threadIdx.x;
    if (i < n) { cnt[i] = 0; fill[i] = 0; }
}

__global__ void k_hist(const int* __restrict__ ei, int* __restrict__ cnt, int E) {
    int e = blockIdx.x * blockDim.x + threadIdx.x;
    if (e < E) atomicAdd(&cnt[ei[E + e]], 1);
}

__global__ void k_dinv(const int* __restrict__ cnt, float* __restrict__ dinv, int n) {
    int i = blockIdx.x * blockDim.x + threadIdx.x;
    if (i < n) dinv[i] = rsqrtf((float)cnt[i] + 1.0f);   // deg includes self loop
}

__global__ void k_scan1(const int* __restrict__ cnt, int* __restrict__ rowptr,
                        int* __restrict__ bsum, int n) {
    __shared__ int sh[256];
    int i = blockIdx.x * 256 + threadIdx.x;
    int v = (i < n) ? cnt[i] : 0;
    sh[threadIdx.x] = v;
    __syncthreads();
    for (int off = 1; off < 256; off <<= 1) {
        int t = (threadIdx.x >= off) ? sh[threadIdx.x - off] : 0;
        __syncthreads();
        sh[threadIdx.x] += t;
        __syncthreads();
    }
    if (i < n) rowptr[i + 1] = sh[threadIdx.x];
    if (threadIdx.x == 255) bsum[blockIdx.x] = sh[255];
}

__global__ void k_scan2(int* __restrict__ bsum, int nb) {
    __shared__ int sh[512];
    int t = threadIdx.x;
    int v = (t < nb) ? bsum[t] : 0;
    sh[t] = v;
    __syncthreads();
    for (int off = 1; off < 512; off <<= 1) {
        int u = (t >= off) ? sh[t - off] : 0;
        __syncthreads();
        sh[t] += u;
        __syncthreads();
    }
    int ex = (t == 0) ? 0 : sh[t - 1];
    if (t < nb) bsum[t] = ex;
}

__global__ void k_scan3(int* __restrict__ rowptr, const int* __restrict__ bsum, int n) {
    int i = blockIdx.x * blockDim.x + threadIdx.x;
    if (i < n) rowptr[i + 1] += bsum[i >> 8];
    if (i == 0) rowptr[0] = 0;
}

__global__ void k_scatter(const int* __restrict__ ei, const float* __restrict__ dinv,
                          const int* __restrict__ rowptr, int* __restrict__ fill,
                          int2* __restrict__ edges, int E) {
    int e = blockIdx.x * blockDim.x + threadIdx.x;
    if (e < E) {
        int s = ei[e], d = ei[E + e];
        float nv = dinv[s] * dinv[d];
        int pos = rowptr[d] + atomicAdd(&fill[d], 1);
        edges[pos] = make_int2(s, __float_as_int(nv));
    }
}

// f32 -> bf16 conversion for weights
__global__ void k_cvt(const float* __restrict__ src, ushort* __restrict__ dst, int n) {
    int i = blockIdx.x * blockDim.x + threadIdx.x;
    if (i < n) dst[i] = (ushort)f2bf(src[i]);
}

// ---------------------------------------------------------------------------
// Fused MFMA MLP: h2 = relu(x@W1^T + b1) @ W2^T + b2  (bf16 in, fp32 accum)
// Block: 256 thr (4 waves), BM=64 rows. Stage1: wave w -> hidden cols
// [64w,64w+64), K-loop BK=64. h1 -> LDS bf16. Stage2: wave w -> rows
// [16w,16w+16), B2 fragments straight from global (L1/L2 broadcast).
// LDS 40KB (w1s 32K @0 | xs 8K @32K; phase2 h1s 32K @0) -> 4 blocks/CU.
// ---------------------------------------------------------------------------
__global__ __launch_bounds__(256, 4) void k_mlp(
    const float* __restrict__ x, const ushort* __restrict__ W1b,
    const float* __restrict__ b1, const ushort* __restrict__ W2b,
    const float* __restrict__ b2, const float* __restrict__ temp,
    ushort* __restrict__ h, float* __restrict__ out, int n)
{
    __shared__ uint4 smem4[2560];            // 40 KB
    char* smem = (char*)smem4;

    const int tid = threadIdx.x;
    const int lane = tid & 63;
    const int w    = tid >> 6;        // wave 0..3
    const int l15  = lane & 15;
    const int l4   = lane >> 4;       // 0..3
    const int row0 = blockIdx.x * 64;

    f32x4 acc[4][4];                  // [rf][nf]
#pragma unroll
    for (int i = 0; i < 4; ++i)
#pragma unroll
        for (int j = 0; j < 4; ++j) acc[i][j] = (f32x4){0.f, 0.f, 0.f, 0.f};

    for (int k0 = 0; k0 < IN_C; k0 += 64) {
        // stage X tile: 64 rows x 64 k, f32 -> bf16, swizzled, at 32K
#pragma unroll
        for (int it = 0; it < 4; ++it) {
            int f  = tid + it * 256;          // float4 slot 0..1023
            int r  = f >> 4;                  // row 0..63
            int c4 = f & 15;                  // float4 idx within row
            int gr = row0 + r; if (gr >= n) gr = n - 1;
            float4 v = *(const float4*)(x + (size_t)gr * IN_C + k0 + c4 * 4);
            uint p0 = f2bf(v.x) | (f2bf(v.y) << 16);
            uint p1 = f2bf(v.z) | (f2bf(v.w) << 16);
            int boff = (c4 * 8) ^ ((r & 7) << 4);
            *(uint2*)(smem + 32768 + r * 128 + boff) = make_uint2(p0, p1);
        }
        // stage W1 tile: 256 rows(hid) x 64 k bf16, swizzled, at 0
#pragma unroll
        for (int it = 0; it < 8; ++it) {
            int m  = tid + it * 256;          // 16B-block 0..2047
            int nn = m >> 3, b = m & 7;
            uint4 v = *(const uint4*)(W1b + (size_t)nn * IN_C + k0 + b * 8);
            int bd = b ^ (nn & 7);
            *(uint4*)(smem + nn * 128 + (bd << 4)) = v;
        }
        __syncthreads();
#pragma unroll
        for (int kk = 0; kk < 2; ++kk) {
            bf16x8 af[4], bfr[4];
            int kb = kk * 4 + l4;             // 16B-block in k
#pragma unroll
            for (int rf = 0; rf < 4; ++rf) {
                int r = rf * 16 + l15;
                af[rf] = *(const bf16x8*)(smem + 32768 + r * 128 + ((kb ^ (r & 7)) << 4));
            }
#pragma unroll
            for (int nf = 0; nf < 4; ++nf) {
                int nn = w * 64 + nf * 16 + l15;
                bfr[nf] = *(const bf16x8*)(smem + nn * 128 + ((kb ^ (nn & 7)) << 4));
            }
#pragma unroll
            for (int rf = 0; rf < 4; ++rf)
#pragma unroll
                for (int nf = 0; nf < 4; ++nf)
                    acc[rf][nf] = __builtin_amdgcn_mfma_f32_16x16x32_bf16(
                        af[rf], bfr[nf], acc[rf][nf], 0, 0, 0);
        }
        __syncthreads();
    }

    // bias + relu -> h1s bf16 swizzled at 0 (overwrites w1s; barrier above done)
    float bias1[4];
#pragma unroll
    for (int nf = 0; nf < 4; ++nf) bias1[nf] = b1[w * 64 + nf * 16 + l15];
#pragma unroll
    for (int rf = 0; rf < 4; ++rf)
#pragma unroll
        for (int nf = 0; nf < 4; ++nf)
#pragma unroll
            for (int j = 0; j < 4; ++j) {
                int r = rf * 16 + l4 * 4 + j;
                int c = w * 64 + nf * 16 + l15;
                float v = fmaxf(acc[rf][nf][j] + bias1[nf], 0.f);
                int byte = r * 512 + ((((c >> 3) ^ (r & 7))) << 4) + (c & 7) * 2;
                *(ushort*)(smem + byte) = (ushort)f2bf(v);
            }
    __syncthreads();

    // stage 2 GEMM: rows slab per wave, K=256; B2 fragments from global
    f32x4 acc2[4];
#pragma unroll
    for (int nf = 0; nf < 4; ++nf) acc2[nf] = (f32x4){0.f, 0.f, 0.f, 0.f};
#pragma unroll
    for (int kk = 0; kk < 8; ++kk) {
        int r = w * 16 + l15;
        int kb = kk * 4 + l4;
        bf16x8 a = *(const bf16x8*)(smem + r * 512 + ((kb ^ (r & 7)) << 4));
#pragma unroll
        for (int nf = 0; nf < 4; ++nf) {
            bf16x8 bb = *(const bf16x8*)(W2b + (size_t)(nf * 16 + l15) * HID_C + kb * 8);
            acc2[nf] = __builtin_amdgcn_mfma_f32_16x16x32_bf16(a, bb, acc2[nf], 0, 0, 0);
        }
    }

    float t0 = temp[0];
#pragma unroll
    for (int nf = 0; nf < 4; ++nf) {
        int c = nf * 16 + l15;
        float bias = b2[c];
#pragma unroll
        for (int j = 0; j < 4; ++j) {
            int gr = row0 + w * 16 + l4 * 4 + j;
            if (gr < n) {
                float v = acc2[nf][j] + bias;
                h[(size_t)gr * OUT_C + c]   = (ushort)f2bf(v);
                out[(size_t)gr * OUT_C + c] = t0 * v;
            }
        }
    }
}

// ---------------------------------------------------------------------------
// One propagation step, gather-form, bf16 state. One wave per dst node.
// 8 lane-groups of 8: group = edge slot, lane-in-group = channel octet
// (bf16x8 = 16B gather). One wave-wide gather instr serves 8 edges (1 KB).
// 3-level shfl_xor reduce; fp32 `out` RMW fused; nxt rounded to bf16.
// ---------------------------------------------------------------------------
__global__ __launch_bounds__(256) void k_prop(
    const int* __restrict__ rowptr, const int2* __restrict__ edges,
    const ushort* __restrict__ cur, ushort* __restrict__ nxt,
    float* __restrict__ out, const float* __restrict__ dinv,
    const float* __restrict__ temp, int k, int n)
{
    const int lane = threadIdx.x & 63;
    const int g    = lane >> 3;          // edge slot 0..7
    const int sl   = lane & 7;           // channel octet 0..7
    const int wid  = (blockIdx.x * blockDim.x + threadIdx.x) >> 6;
    const int nw   = (gridDim.x * blockDim.x) >> 6;
    const float gamma = temp[k];

    for (int d = wid; d < n; d += nw) {
        const int b = rowptr[d], en = rowptr[d + 1];
        const float di = dinv[d];
        float a[8] = {0.f, 0.f, 0.f, 0.f, 0.f, 0.f, 0.f, 0.f};

        if (g == 0) {                     // self-loop term, counted once
            uint4 raw = *(const uint4*)(cur + (size_t)d * OUT_C + sl * 8);
            float s = di * di;
            a[0] = s * bfl(raw.x); a[1] = s * bfh(raw.x);
            a[2] = s * bfl(raw.y); a[3] = s * bfh(raw.y);
            a[4] = s * bfl(raw.z); a[5] = s * bfh(raw.z);
            a[6] = s * bfl(raw.w); a[7] = s * bfh(raw.w);
        }

        for (int i = b + g; i < en; i += 8) {
            int2 e = edges[i];
            float wv = __int_as_float(e.y);
            uint4 raw = *(const uint4*)(cur + (size_t)e.x * OUT_C + sl * 8);
            a[0] = fmaf(wv, bfl(raw.x), a[0]); a[1] = fmaf(wv, bfh(raw.x), a[1]);
            a[2] = fmaf(wv, bfl(raw.y), a[2]); a[3] = fmaf(wv, bfh(raw.y), a[3]);
            a[4] = fmaf(wv, bfl(raw.z), a[4]); a[5] = fmaf(wv, bfh(raw.z), a[5]);
            a[6] = fmaf(wv, bfl(raw.w), a[6]); a[7] = fmaf(wv, bfh(raw.w), a[7]);
        }

#pragma unroll
        for (int j = 0; j < 8; ++j) {
            a[j] += __shfl_xor(a[j], 8);
            a[j] += __shfl_xor(a[j], 16);
            a[j] += __shfl_xor(a[j], 32);
        }

        if (g == 0) {
            size_t o = (size_t)d * OUT_C + sl * 8;
            uint4 pk;
            pk.x = f2bf(a[0]) | (f2bf(a[1]) << 16);
            pk.y = f2bf(a[2]) | (f2bf(a[3]) << 16);
            pk.z = f2bf(a[4]) | (f2bf(a[5]) << 16);
            pk.w = f2bf(a[6]) | (f2bf(a[7]) << 16);
            *(uint4*)(nxt + o) = pk;
            float4* op = (float4*)(out + o);
            float4 v0 = op[0], v1 = op[1];
            v0.x += gamma * a[0]; v0.y += gamma * a[1];
            v0.z += gamma * a[2]; v0.w += gamma * a[3];
            v1.x += gamma * a[4]; v1.y += gamma * a[5];
            v1.z += gamma * a[6]; v1.w += gamma * a[7];
            op[0] = v0; op[1] = v1;
        }
    }
}

// ---------------------------------------------------------------------------
extern "C" void kernel_launch(void* const* d_in, const int* in_sizes, int n_in,
                              void* d_out, int out_size, void* d_ws, size_t ws_size,
                              hipStream_t stream)
{
    const float* x    = (const float*)d_in[0];
    const int*   ei   = (const int*)d_in[1];
    const float* W1   = (const float*)d_in[2];
    const float* b1   = (const float*)d_in[3];
    const float* W2   = (const float*)d_in[4];
    const float* b2   = (const float*)d_in[5];
    const float* temp = (const float*)d_in[6];
    float* out = (float*)d_out;

    const int N = in_sizes[0] / IN_C;
    const int E = in_sizes[1] / 2;

    // workspace layout
    char* ws = (char*)d_ws;
    ushort* bufA  = (ushort*)ws;                       // N*64 bf16
    ushort* bufB  = bufA + (size_t)N * OUT_C;          // N*64 bf16
    int2*   edges = (int2*)(bufB + (size_t)N * OUT_C); // E int2
    ushort* W1b   = (ushort*)(edges + E);
    ushort* W2b   = W1b + HID_C * IN_C;
    float*  dinv  = (float*)(W2b + OUT_C * HID_C);
    int*    cnt    = (int*)(dinv + N);
    int*    fill   = cnt + N;
    int*    rowptr = fill + N;
    int*    bsum   = rowptr + (N + 16);

    const int nbN = (N + 255) / 256;
    const int nbE = (E + 255) / 256;

    k_init   <<<nbN, 256, 0, stream>>>(cnt, fill, N);
    k_hist   <<<nbE, 256, 0, stream>>>(ei, cnt, E);
    k_dinv   <<<nbN, 256, 0, stream>>>(cnt, dinv, N);
    k_scan1  <<<nbN, 256, 0, stream>>>(cnt, rowptr, bsum, N);
    k_scan2  <<<1,   512, 0, stream>>>(bsum, nbN);
    k_scan3  <<<nbN, 256, 0, stream>>>(rowptr, bsum, N);
    k_scatter<<<nbE, 256, 0, stream>>>(ei, dinv, rowptr, fill, edges, E);
    k_cvt    <<<(HID_C * IN_C + 255) / 256, 256, 0, stream>>>(W1, W1b, HID_C * IN_C);
    k_cvt    <<<(OUT_C * HID_C + 255) / 256, 256, 0, stream>>>(W2, W2b, OUT_C * HID_C);

    k_mlp<<<(N + 63) / 64, 256, 0, stream>>>(x, W1b, b1, W2b, b2, temp, bufA, out, N);

    ushort* cur = bufA;
    ushort* nxt = bufB;
    for (int k = 1; k <= KSTEPS; ++k) {
        k_prop<<<2048, 256, 0, stream>>>(rowptr, edges, cur, nxt, out, dinv, temp, k, N);
        ushort* t = cur; cur = nxt; nxt = t;
    }
}